// Round 9
// baseline (3038.701 us; speedup 1.0000x reference)
//
#include <hip/hip_runtime.h>

// LSTM surrogate: B=256, T=512, D=256, U=512, O=64.
// R9: overlap-restructure of R8 (same proven swap-at-L3 coherence protocol):
//  - publish phase: waves0-1 pointwise+swap  ||  waves2-3 x-stage + y-decode
//  - consume phase: per-producer flag-gated subtile loads (arrival order),
//    own subtile written LDS-direct from registers
//  - x-part MFMA (K=0..255) precomputed for t+1 in the consume window
//  - 3 barriers/step (was 5)
// 16 batch-groups x 16 rows, 32 unit-groups -> grid 512, 2 blocks/CU.

#define Bb 256
#define Tt 512
#define Dd 256
#define Uu 512
#define Oo 64

typedef short bs8 __attribute__((ext_vector_type(8)));      // 8 bf16 (bits)
typedef float f32x4 __attribute__((ext_vector_type(4)));

__device__ __forceinline__ unsigned short f2bf(float f) {
  unsigned u = __float_as_uint(f);
  u += 0x7fffu + ((u >> 16) & 1u);                          // RNE
  return (unsigned short)(u >> 16);
}
__device__ __forceinline__ float bf2f(unsigned short s) {
  return __uint_as_float(((unsigned)s) << 16);
}
__device__ __forceinline__ float sigm(float v) { return 1.0f / (1.0f + __expf(-v)); }
__device__ __forceinline__ float tanhfast(float v) { return 2.0f / (1.0f + __expf(-2.0f * v)) - 1.0f; }

// z LDS: [16 rows][768 k] bf16, row stride 1536 B. XOR swizzle on 16B granules.
__device__ __forceinline__ int zbyte(int row, int k) {
  return (row * 1536 + k * 2) ^ ((row & 7) << 4);
}

__global__ void rnn_init_bar(unsigned* bar) {
  __hip_atomic_store(&bar[threadIdx.x], 0u, __ATOMIC_RELAXED, __HIP_MEMORY_SCOPE_AGENT);
}

__launch_bounds__(256, 2)
__global__ void rnn_lstm_kernel(const float* __restrict__ x, const float* __restrict__ Wx,
                                const float* __restrict__ Wh, const float* __restrict__ bias,
                                const float* __restrict__ Wd, const float* __restrict__ bd,
                                float* __restrict__ out, unsigned short* hbuf, unsigned* bar) {
  __shared__ __align__(16) char zs[16 * 768 * 2];   // 24576 B
  __shared__ float gates[4][16][17];                // [gate][row][unit], pad
  __shared__ float wdl[512][2];                     // Wd slice for this block's 2 out cols
  __shared__ float ypart[16][2][8];                 // [row][oc][sec]

  const int tid = threadIdx.x;
  const int lane = tid & 63;
  const int wid = tid >> 6;                         // wave 0..3 == gate id
  const int bid = blockIdx.x;
  const int bg = (bid & 7) | ((bid >> 8) << 3);     // 0..15 (XCD-affine heuristic)
  const int ug = (bid >> 3) & 31;                   // 0..31
  const int b_base = bg * 16;
  const int u_base = ug * 16;
  const int oc0 = ug * 2;

  unsigned* fl = bar + bg * 32;  // 32 per-block flags, one 128B line per group

  // ---- weight slice as B-fragments: wave w = gate w; col=lane&15, k=(lane>>4)*8+e ----
  bs8 breg[24];
  {
    const int gc = wid * 512 + u_base + (lane & 15);
    const int kfr = (lane >> 4) * 8;
#pragma unroll
    for (int ks = 0; ks < 24; ++ks) {
      bs8 bb;
#pragma unroll
      for (int e = 0; e < 8; ++e) {
        int kg = ks * 32 + kfr + e;
        float w = (kg < 256) ? Wx[(size_t)kg * 2048 + gc]
                             : Wh[(size_t)(kg - 256) * 2048 + gc];
        bb[e] = (short)f2bf(w);
      }
      breg[ks] = bb;
    }
  }

  // pointwise (tid<128): prow=tid&15, up=tid>>4 (0..7), units up*2+{0,1}
  const int prow = tid & 15;
  const int up = tid >> 4;
  float bi[2], bff[2], bgg[2], boo[2];
  if (tid < 128) {
#pragma unroll
    for (int j = 0; j < 2; ++j) {
      int ugl = u_base + up * 2 + j;
      bi[j]  = bias[0 * 512 + ugl];
      bff[j] = bias[1 * 512 + ugl];
      bgg[j] = bias[2 * 512 + ugl];
      boo[j] = bias[3 * 512 + ugl];
    }
  }
  float cst[2] = {0.f, 0.f};

  // ---- prologue: Wd->LDS, stage x_0, zero h-region, x-MFMA(0) ----
#pragma unroll
  for (int i = 0; i < 4; ++i) {
    int c = tid + i * 256;
    int u = c >> 1, oc = c & 1;
    wdl[u][oc] = Wd[(size_t)u * Oo + oc0 + oc];
  }
  {
    int row = tid >> 4;
    int d0 = (tid & 15) * 16;
    const float* xp = x + ((size_t)(b_base + row) * Tt + 0) * Dd + d0;
    float4 v0 = *(const float4*)xp;
    float4 v1 = *(const float4*)(xp + 4);
    float4 v2 = *(const float4*)(xp + 8);
    float4 v3 = *(const float4*)(xp + 12);
    bs8 p0, p1;
    p0[0] = (short)f2bf(v0.x); p0[1] = (short)f2bf(v0.y);
    p0[2] = (short)f2bf(v0.z); p0[3] = (short)f2bf(v0.w);
    p0[4] = (short)f2bf(v1.x); p0[5] = (short)f2bf(v1.y);
    p0[6] = (short)f2bf(v1.z); p0[7] = (short)f2bf(v1.w);
    p1[0] = (short)f2bf(v2.x); p1[1] = (short)f2bf(v2.y);
    p1[2] = (short)f2bf(v2.z); p1[3] = (short)f2bf(v2.w);
    p1[4] = (short)f2bf(v3.x); p1[5] = (short)f2bf(v3.y);
    p1[6] = (short)f2bf(v3.z); p1[7] = (short)f2bf(v3.w);
    *(bs8*)(zs + zbyte(row, d0)) = p0;
    *(bs8*)(zs + zbyte(row, d0 + 8)) = p1;
  }
#pragma unroll
  for (int i = 0; i < 4; ++i) {
    int c = tid + i * 256;
    int row = c >> 6;
    int u0 = (c & 63) * 8;
    bs8 zz = {0, 0, 0, 0, 0, 0, 0, 0};
    *(bs8*)(zs + zbyte(row, 256 + u0)) = zz;
  }
  __syncthreads();

  const int arow = lane & 15;
  const int akf = (lane >> 4) * 8;
  f32x4 accx0 = {0, 0, 0, 0}, accx1 = {0, 0, 0, 0};
#pragma unroll
  for (int ks = 0; ks < 8; ks += 2) {
    bs8 av0 = *(const bs8*)(zs + zbyte(arow, ks * 32 + akf));
    bs8 av1 = *(const bs8*)(zs + zbyte(arow, (ks + 1) * 32 + akf));
    accx0 = __builtin_amdgcn_mfma_f32_16x16x32_bf16(av0, breg[0], accx0, 0, 0, 0);
    accx1 = __builtin_amdgcn_mfma_f32_16x16x32_bf16(av1, breg[1], accx1, 0, 0, 0);
    // NOTE: indices must match ks; rewritten below properly
  }
  // redo correctly (compiler folds; keep simple + correct):
  accx0 = (f32x4){0, 0, 0, 0}; accx1 = (f32x4){0, 0, 0, 0};
#pragma unroll
  for (int ks = 0; ks < 8; ks += 2) {
    bs8 av0 = *(const bs8*)(zs + zbyte(arow, ks * 32 + akf));
    bs8 av1 = *(const bs8*)(zs + zbyte(arow, (ks + 1) * 32 + akf));
    accx0 = __builtin_amdgcn_mfma_f32_16x16x32_bf16(av0, breg[ks], accx0, 0, 0, 0);
    accx1 = __builtin_amdgcn_mfma_f32_16x16x32_bf16(av1, breg[ks + 1], accx1, 0, 0, 0);
  }

  for (int t = 0; t < Tt; ++t) {
    // ---- h-part MFMA (K=256..767), seeded with precomputed x-part ----
    f32x4 acc0 = accx0, acc1 = accx1;
#pragma unroll
    for (int ks = 8; ks < 24; ks += 2) {
      bs8 av0 = *(const bs8*)(zs + zbyte(arow, ks * 32 + akf));
      bs8 av1 = *(const bs8*)(zs + zbyte(arow, (ks + 1) * 32 + akf));
      acc0 = __builtin_amdgcn_mfma_f32_16x16x32_bf16(av0, breg[ks], acc0, 0, 0, 0);
      acc1 = __builtin_amdgcn_mfma_f32_16x16x32_bf16(av1, breg[ks + 1], acc1, 0, 0, 0);
    }
    acc0 += acc1;
    {
      const int u16 = lane & 15;
      const int rb = (lane >> 4) * 4;
#pragma unroll
      for (int j = 0; j < 4; ++j) gates[wid][rb + j][u16] = acc0[j];
    }
    __syncthreads();                                        // s1

    // ---- publish phase: waves0-1 pointwise+swap || waves2-3 x-stage + y-decode ----
    unsigned hpack = 0;
    if (tid < 128) {
#pragma unroll
      for (int j = 0; j < 2; ++j) {
        int u = up * 2 + j;
        float gi = gates[0][prow][u] + bi[j];
        float gf = gates[1][prow][u] + bff[j];
        float gg = gates[2][prow][u] + bgg[j];
        float go = gates[3][prow][u] + boo[j];
        float iv = sigm(gi), fv = sigm(gf), gv = tanhfast(gg), ov = sigm(go);
        float cn = fv * cst[j] + iv * gv;
        cst[j] = cn;
        float hv = ov * tanhfast(cn);
        hpack |= ((unsigned)f2bf(hv)) << (16 * j);
      }
      unsigned* hp = (unsigned*)(hbuf + (size_t)(t & 1) * Bb * Uu +
                                 (size_t)(b_base + prow) * Uu + u_base + up * 2);
      unsigned old = __hip_atomic_exchange(hp, hpack, __ATOMIC_RELAXED,
                                           __HIP_MEMORY_SCOPE_AGENT);
      asm volatile("" :: "v"(old));   // keep the returning (at-L3) form
    } else {
      int t2 = tid - 128;
      if (t + 1 < Tt) {               // x-stage x_{t+1}: 16 rows x 8 lanes x 32 floats
        int row = t2 >> 3;
        int d0 = (t2 & 7) * 32;
        const float* xp = x + ((size_t)(b_base + row) * Tt + (t + 1)) * Dd + d0;
#pragma unroll
        for (int q = 0; q < 4; ++q) {
          float4 va = *(const float4*)(xp + q * 8);
          float4 vb = *(const float4*)(xp + q * 8 + 4);
          bs8 pk;
          pk[0] = (short)f2bf(va.x); pk[1] = (short)f2bf(va.y);
          pk[2] = (short)f2bf(va.z); pk[3] = (short)f2bf(va.w);
          pk[4] = (short)f2bf(vb.x); pk[5] = (short)f2bf(vb.y);
          pk[6] = (short)f2bf(vb.z); pk[7] = (short)f2bf(vb.w);
          *(bs8*)(zs + zbyte(row, d0 + q * 8)) = pk;
        }
      }
      if (t > 0) {                    // y_{t-1} decode: 16 rows x 8 secs x 64 units
        int row = t2 & 15;
        int sec = t2 >> 4;
        float s0 = 0.f, s1 = 0.f;
#pragma unroll
        for (int c8 = 0; c8 < 8; ++c8) {
          int k = 256 + sec * 64 + c8 * 8;
          bs8 hv = *(const bs8*)(zs + zbyte(row, k));
#pragma unroll
          for (int e = 0; e < 8; ++e) {
            float hf = bf2f((unsigned short)hv[e]);
            int u = sec * 64 + c8 * 8 + e;
            s0 += hf * wdl[u][0];
            s1 += hf * wdl[u][1];
          }
        }
        ypart[row][0][sec] = s0;
        ypart[row][1][sec] = s1;
      }
    }
    __syncthreads();                                        // s2 (drains swaps at L3)
    if (tid == 0) {
      unsigned oldf = __hip_atomic_exchange(&fl[ug], (unsigned)(t + 1),
                                            __ATOMIC_RELAXED, __HIP_MEMORY_SCOPE_AGENT);
      asm volatile("" :: "v"(oldf));
    }
    // own h subtile LDS-direct from registers (skip own L3 round trip)
    if (tid < 128)
      *(unsigned*)(zs + zbyte(prow, 256 + u_base + up * 2)) = hpack;

    // x-part MFMA for t+1 (reads zs.x staged pre-s2)
    if (t + 1 < Tt) {
      f32x4 ax0 = {0, 0, 0, 0}, ax1 = {0, 0, 0, 0};
#pragma unroll
      for (int ks = 0; ks < 8; ks += 2) {
        bs8 av0 = *(const bs8*)(zs + zbyte(arow, ks * 32 + akf));
        bs8 av1 = *(const bs8*)(zs + zbyte(arow, (ks + 1) * 32 + akf));
        ax0 = __builtin_amdgcn_mfma_f32_16x16x32_bf16(av0, breg[ks], ax0, 0, 0, 0);
        ax1 = __builtin_amdgcn_mfma_f32_16x16x32_bf16(av1, breg[ks + 1], ax1, 0, 0, 0);
      }
      accx0 = ax0; accx1 = ax1;
    }
    // y-reduce (wave0 lanes 0-31)
    if (t > 0 && tid < 32) {
      int b = tid >> 1, oc = tid & 1;
      float s = bd[oc0 + oc];
#pragma unroll
      for (int q = 0; q < 8; ++q) s += ypart[b][oc][q];
      out[((size_t)(b_base + b) * Tt + (t - 1)) * Oo + oc0 + oc] = s;
    }

    // ---- consume: per-producer flag-gated subtile loads, arrival order ----
    {
      const unsigned short* hsrc = hbuf + (size_t)(t & 1) * Bb * Uu;
      const int pbase = wid * 8;
      const int pi = lane & 7;
      const int crow = lane >> 2;
      const int cq = lane & 3;
      unsigned done = (ug >= pbase && ug < pbase + 8) ? (1u << (ug - pbase)) : 0u;
      while (done != 0xffu) {
        unsigned v = __hip_atomic_load(&fl[pbase + pi], __ATOMIC_RELAXED,
                                       __HIP_MEMORY_SCOPE_AGENT);
        unsigned long long rdy = __ballot((int)(v >= (unsigned)(t + 1)));
        unsigned ready8 = ((unsigned)rdy & 0xffu) & ~done;
        while (ready8) {
          int i = __ffs(ready8) - 1;
          ready8 &= ready8 - 1;
          int p = pbase + i;
          const unsigned long long* src = (const unsigned long long*)
              (hsrc + (size_t)(b_base + crow) * Uu + p * 16 + cq * 4);
          unsigned long long d = __hip_atomic_load(src, __ATOMIC_RELAXED,
                                                   __HIP_MEMORY_SCOPE_AGENT);
          *(unsigned long long*)(zs + zbyte(crow, 256 + p * 16 + cq * 4)) = d;
          done |= 1u << i;
        }
      }
    }
    __syncthreads();                                        // s3
  }

  // ---- epilogue: y_{T-1} from zs.h (= h_{T-1} after final consume) ----
  if (tid >= 128) {
    int t2 = tid - 128;
    int row = t2 & 15;
    int sec = t2 >> 4;
    float s0 = 0.f, s1 = 0.f;
#pragma unroll
    for (int c8 = 0; c8 < 8; ++c8) {
      int k = 256 + sec * 64 + c8 * 8;
      bs8 hv = *(const bs8*)(zs + zbyte(row, k));
#pragma unroll
      for (int e = 0; e < 8; ++e) {
        float hf = bf2f((unsigned short)hv[e]);
        int u = sec * 64 + c8 * 8 + e;
        s0 += hf * wdl[u][0];
        s1 += hf * wdl[u][1];
      }
    }
    ypart[row][0][sec] = s0;
    ypart[row][1][sec] = s1;
  }
  __syncthreads();
  if (tid < 32) {
    int b = tid >> 1, oc = tid & 1;
    float s = bd[oc0 + oc];
#pragma unroll
    for (int q = 0; q < 8; ++q) s += ypart[b][oc][q];
    out[((size_t)(b_base + b) * Tt + (Tt - 1)) * Oo + oc0 + oc] = s;
  }
}

extern "C" void kernel_launch(void* const* d_in, const int* in_sizes, int n_in,
                              void* d_out, int out_size, void* d_ws, size_t ws_size,
                              hipStream_t stream) {
  const float* x  = (const float*)d_in[0];
  const float* Wx = (const float*)d_in[1];
  const float* Wh = (const float*)d_in[2];
  const float* bs = (const float*)d_in[3];
  const float* Wd = (const float*)d_in[4];
  const float* bd = (const float*)d_in[5];
  float* out = (float*)d_out;

  unsigned short* hbuf = (unsigned short*)d_ws;                       // 2*256*512 bf16 = 512 KiB
  unsigned* bar = (unsigned*)((char*)d_ws + (size_t)2 * Bb * Uu * 2); // 16 groups * 32 flags

  rnn_init_bar<<<1, 512, 0, stream>>>(bar);
  rnn_lstm_kernel<<<dim3(512), dim3(256), 0, stream>>>(x, Wx, Wh, bs, Wd, bd, out, hbuf, bar);
}

// Round 10
// 2849.935 us; speedup vs baseline: 1.0662x; 1.0662x over previous
//
#include <hip/hip_runtime.h>

// LSTM surrogate: B=256, T=512, D=256, U=512, O=64.
// R10 = R8's proven consume (monolithic poll + bulk PARALLEL h-load; R9's
// arrival-ordered loop serialized 8 L3 RTs and regressed) + R9's proven
// overlaps (publish-phase wave specialization, x-part MFMA precompute).
// 4 barriers/step. Swap-at-L3 coherence protocol (R8) unchanged.
// 16 batch-groups x 16 rows, 32 unit-groups -> grid 512, 2 blocks/CU.

#define Bb 256
#define Tt 512
#define Dd 256
#define Uu 512
#define Oo 64

typedef short bs8 __attribute__((ext_vector_type(8)));      // 8 bf16 (bits)
typedef float f32x4 __attribute__((ext_vector_type(4)));

__device__ __forceinline__ unsigned short f2bf(float f) {
  unsigned u = __float_as_uint(f);
  u += 0x7fffu + ((u >> 16) & 1u);                          // RNE
  return (unsigned short)(u >> 16);
}
__device__ __forceinline__ float bf2f(unsigned short s) {
  return __uint_as_float(((unsigned)s) << 16);
}
__device__ __forceinline__ float sigm(float v) { return 1.0f / (1.0f + __expf(-v)); }
__device__ __forceinline__ float tanhfast(float v) { return 2.0f / (1.0f + __expf(-2.0f * v)) - 1.0f; }

// z LDS: [16 rows][768 k] bf16, row stride 1536 B. XOR swizzle on 16B granules.
__device__ __forceinline__ int zbyte(int row, int k) {
  return (row * 1536 + k * 2) ^ ((row & 7) << 4);
}

__global__ void rnn_init_bar(unsigned* bar) {
  __hip_atomic_store(&bar[threadIdx.x], 0u, __ATOMIC_RELAXED, __HIP_MEMORY_SCOPE_AGENT);
}

__launch_bounds__(256, 2)
__global__ void rnn_lstm_kernel(const float* __restrict__ x, const float* __restrict__ Wx,
                                const float* __restrict__ Wh, const float* __restrict__ bias,
                                const float* __restrict__ Wd, const float* __restrict__ bd,
                                float* __restrict__ out, unsigned short* hbuf, unsigned* bar) {
  __shared__ __align__(16) char zs[16 * 768 * 2];   // 24576 B
  __shared__ float gates[4][16][17];                // [gate][row][unit], pad
  __shared__ float wdl[512][2];                     // Wd slice for this block's 2 out cols
  __shared__ float ypart[16][2][8];                 // [row][oc][sec]

  const int tid = threadIdx.x;
  const int lane = tid & 63;
  const int wid = tid >> 6;                         // wave 0..3 == gate id
  const int bid = blockIdx.x;
  const int bg = (bid & 7) | ((bid >> 8) << 3);     // 0..15 (XCD-affine heuristic)
  const int ug = (bid >> 3) & 31;                   // 0..31
  const int b_base = bg * 16;
  const int u_base = ug * 16;
  const int oc0 = ug * 2;

  unsigned* fl = bar + bg * 32;  // 32 per-block flags, one 128B line per group

  // ---- weight slice as B-fragments: wave w = gate w; col=lane&15, k=(lane>>4)*8+e ----
  bs8 breg[24];
  {
    const int gc = wid * 512 + u_base + (lane & 15);
    const int kfr = (lane >> 4) * 8;
#pragma unroll
    for (int ks = 0; ks < 24; ++ks) {
      bs8 bb;
#pragma unroll
      for (int e = 0; e < 8; ++e) {
        int kg = ks * 32 + kfr + e;
        float w = (kg < 256) ? Wx[(size_t)kg * 2048 + gc]
                             : Wh[(size_t)(kg - 256) * 2048 + gc];
        bb[e] = (short)f2bf(w);
      }
      breg[ks] = bb;
    }
  }

  // pointwise (tid<128): prow=tid&15, up=tid>>4 (0..7), units up*2+{0,1}
  const int prow = tid & 15;
  const int up = tid >> 4;
  float bi[2], bff[2], bgg[2], boo[2];
  if (tid < 128) {
#pragma unroll
    for (int j = 0; j < 2; ++j) {
      int ugl = u_base + up * 2 + j;
      bi[j]  = bias[0 * 512 + ugl];
      bff[j] = bias[1 * 512 + ugl];
      bgg[j] = bias[2 * 512 + ugl];
      boo[j] = bias[3 * 512 + ugl];
    }
  }
  float cst[2] = {0.f, 0.f};

  union U16 { unsigned long long q[2]; bs8 v; };

  // ---- prologue: Wd->LDS, stage x_0, zero h-region ----
#pragma unroll
  for (int i = 0; i < 4; ++i) {
    int c = tid + i * 256;
    int u = c >> 1, oc = c & 1;
    wdl[u][oc] = Wd[(size_t)u * Oo + oc0 + oc];
  }
  {
    int row = tid >> 4;
    int d0 = (tid & 15) * 16;
    const float* xp = x + ((size_t)(b_base + row) * Tt + 0) * Dd + d0;
    float4 v0 = *(const float4*)xp;
    float4 v1 = *(const float4*)(xp + 4);
    float4 v2 = *(const float4*)(xp + 8);
    float4 v3 = *(const float4*)(xp + 12);
    bs8 p0, p1;
    p0[0] = (short)f2bf(v0.x); p0[1] = (short)f2bf(v0.y);
    p0[2] = (short)f2bf(v0.z); p0[3] = (short)f2bf(v0.w);
    p0[4] = (short)f2bf(v1.x); p0[5] = (short)f2bf(v1.y);
    p0[6] = (short)f2bf(v1.z); p0[7] = (short)f2bf(v1.w);
    p1[0] = (short)f2bf(v2.x); p1[1] = (short)f2bf(v2.y);
    p1[2] = (short)f2bf(v2.z); p1[3] = (short)f2bf(v2.w);
    p1[4] = (short)f2bf(v3.x); p1[5] = (short)f2bf(v3.y);
    p1[6] = (short)f2bf(v3.z); p1[7] = (short)f2bf(v3.w);
    *(bs8*)(zs + zbyte(row, d0)) = p0;
    *(bs8*)(zs + zbyte(row, d0 + 8)) = p1;
  }
#pragma unroll
  for (int i = 0; i < 4; ++i) {
    int c = tid + i * 256;
    int row = c >> 6;
    int u0 = (c & 63) * 8;
    bs8 zz = {0, 0, 0, 0, 0, 0, 0, 0};
    *(bs8*)(zs + zbyte(row, 256 + u0)) = zz;
  }
  __syncthreads();

  const int arow = lane & 15;
  const int akf = (lane >> 4) * 8;
  // x-part MFMA for t=0 (K=0..255)
  f32x4 accx0 = {0, 0, 0, 0}, accx1 = {0, 0, 0, 0};
#pragma unroll
  for (int ks = 0; ks < 8; ks += 2) {
    bs8 av0 = *(const bs8*)(zs + zbyte(arow, ks * 32 + akf));
    bs8 av1 = *(const bs8*)(zs + zbyte(arow, (ks + 1) * 32 + akf));
    accx0 = __builtin_amdgcn_mfma_f32_16x16x32_bf16(av0, breg[ks], accx0, 0, 0, 0);
    accx1 = __builtin_amdgcn_mfma_f32_16x16x32_bf16(av1, breg[ks + 1], accx1, 0, 0, 0);
  }

  for (int t = 0; t < Tt; ++t) {
    // ---- h-part MFMA (K=256..767), seeded with precomputed x-part ----
    f32x4 acc0 = accx0, acc1 = accx1;
#pragma unroll
    for (int ks = 8; ks < 24; ks += 2) {
      bs8 av0 = *(const bs8*)(zs + zbyte(arow, ks * 32 + akf));
      bs8 av1 = *(const bs8*)(zs + zbyte(arow, (ks + 1) * 32 + akf));
      acc0 = __builtin_amdgcn_mfma_f32_16x16x32_bf16(av0, breg[ks], acc0, 0, 0, 0);
      acc1 = __builtin_amdgcn_mfma_f32_16x16x32_bf16(av1, breg[ks + 1], acc1, 0, 0, 0);
    }
    acc0 += acc1;
    // C/D (HW-verified): col = lane&15, row = (lane>>4)*4 + reg
    {
      const int u16 = lane & 15;
      const int rb = (lane >> 4) * 4;
#pragma unroll
      for (int j = 0; j < 4; ++j) gates[wid][rb + j][u16] = acc0[j];
    }
    __syncthreads();                                        // s1

    // ---- publish: waves0-1 pointwise+swap || waves2-3 x-stage + y-decode ----
    if (tid < 128) {
      unsigned hpack = 0;
#pragma unroll
      for (int j = 0; j < 2; ++j) {
        int u = up * 2 + j;
        float gi = gates[0][prow][u] + bi[j];
        float gf = gates[1][prow][u] + bff[j];
        float gg = gates[2][prow][u] + bgg[j];
        float go = gates[3][prow][u] + boo[j];
        float iv = sigm(gi), fv = sigm(gf), gv = tanhfast(gg), ov = sigm(go);
        float cn = fv * cst[j] + iv * gv;
        cst[j] = cn;
        float hv = ov * tanhfast(cn);
        hpack |= ((unsigned)f2bf(hv)) << (16 * j);
      }
      unsigned* hp = (unsigned*)(hbuf + (size_t)(t & 1) * Bb * Uu +
                                 (size_t)(b_base + prow) * Uu + u_base + up * 2);
      unsigned old = __hip_atomic_exchange(hp, hpack, __ATOMIC_RELAXED,
                                           __HIP_MEMORY_SCOPE_AGENT);
      asm volatile("" :: "v"(old));   // keep the returning (executes-at-L3) form
    } else {
      int t2 = tid - 128;
      if (t + 1 < Tt) {               // x-stage x_{t+1}: row=t2>>3, 32 floats each
        int row = t2 >> 3;
        int d0 = (t2 & 7) * 32;
        const float* xp = x + ((size_t)(b_base + row) * Tt + (t + 1)) * Dd + d0;
#pragma unroll
        for (int q = 0; q < 4; ++q) {
          float4 va = *(const float4*)(xp + q * 8);
          float4 vb = *(const float4*)(xp + q * 8 + 4);
          bs8 pk;
          pk[0] = (short)f2bf(va.x); pk[1] = (short)f2bf(va.y);
          pk[2] = (short)f2bf(va.z); pk[3] = (short)f2bf(va.w);
          pk[4] = (short)f2bf(vb.x); pk[5] = (short)f2bf(vb.y);
          pk[6] = (short)f2bf(vb.z); pk[7] = (short)f2bf(vb.w);
          *(bs8*)(zs + zbyte(row, d0 + q * 8)) = pk;
        }
      }
      if (t > 0) {                    // y_{t-1} decode from zs.h (= h_{t-1})
        int row = t2 & 15;
        int sec = t2 >> 4;            // 0..7, 64 units each
        float s0 = 0.f, s1 = 0.f;
#pragma unroll
        for (int c8 = 0; c8 < 8; ++c8) {
          int k = 256 + sec * 64 + c8 * 8;
          bs8 hv = *(const bs8*)(zs + zbyte(row, k));
#pragma unroll
          for (int e = 0; e < 8; ++e) {
            float hf = bf2f((unsigned short)hv[e]);
            int u = sec * 64 + c8 * 8 + e;
            s0 += hf * wdl[u][0];
            s1 += hf * wdl[u][1];
          }
        }
        ypart[row][0][sec] = s0;
        ypart[row][1][sec] = s1;
      }
    }
    __syncthreads();                                        // s2 (drains swaps at L3)
    if (tid == 0) {
      unsigned oldf = __hip_atomic_exchange(&fl[ug], (unsigned)(t + 1),
                                            __ATOMIC_RELAXED, __HIP_MEMORY_SCOPE_AGENT);
      asm volatile("" :: "v"(oldf));
    }

    // ---- overlap window: x-part MFMA for t+1 (all waves) + y-reduce + poll ----
    if (t + 1 < Tt) {
      f32x4 ax0 = {0, 0, 0, 0}, ax1 = {0, 0, 0, 0};
#pragma unroll
      for (int ks = 0; ks < 8; ks += 2) {
        bs8 av0 = *(const bs8*)(zs + zbyte(arow, ks * 32 + akf));
        bs8 av1 = *(const bs8*)(zs + zbyte(arow, (ks + 1) * 32 + akf));
        ax0 = __builtin_amdgcn_mfma_f32_16x16x32_bf16(av0, breg[ks], ax0, 0, 0, 0);
        ax1 = __builtin_amdgcn_mfma_f32_16x16x32_bf16(av1, breg[ks + 1], ax1, 0, 0, 0);
      }
      accx0 = ax0; accx1 = ax1;
    }
    if (t > 0 && tid < 32) {          // y-reduce (wave0)
      int b = tid >> 1, oc = tid & 1;
      float s = bd[oc0 + oc];
#pragma unroll
      for (int q = 0; q < 8; ++q) s += ypart[b][oc][q];
      out[((size_t)(b_base + b) * Tt + (t - 1)) * Oo + oc0 + oc] = s;
    }
    if (wid == 1) {                   // poll (wave1): one coalesced request/iter
      unsigned v;
      do {
        v = __hip_atomic_load(&fl[lane & 31], __ATOMIC_RELAXED, __HIP_MEMORY_SCOPE_AGENT);
      } while (__any((int)(v < (unsigned)(t + 1))));
    }
    __builtin_amdgcn_sched_barrier(0);
    __syncthreads();                                        // s3

    // ---- bulk h-load: all 256 threads, all loads independent & in flight ----
    {
      const unsigned short* hsrc = hbuf + (size_t)(t & 1) * Bb * Uu;
#pragma unroll
      for (int i = 0; i < 4; ++i) {
        int c = tid + i * 256;
        int row = c >> 6;
        int u0 = (c & 63) * 8;
        const unsigned long long* p =
            (const unsigned long long*)(hsrc + (size_t)(b_base + row) * Uu + u0);
        U16 uu;
        uu.q[0] = __hip_atomic_load(p, __ATOMIC_RELAXED, __HIP_MEMORY_SCOPE_AGENT);
        uu.q[1] = __hip_atomic_load(p + 1, __ATOMIC_RELAXED, __HIP_MEMORY_SCOPE_AGENT);
        *(bs8*)(zs + zbyte(row, 256 + u0)) = uu.v;
      }
    }
    __syncthreads();                                        // s4
  }

  // ---- epilogue: y_{T-1} from zs.h (= h_{T-1} after final bulk load) ----
  if (tid >= 128) {
    int t2 = tid - 128;
    int row = t2 & 15;
    int sec = t2 >> 4;
    float s0 = 0.f, s1 = 0.f;
#pragma unroll
    for (int c8 = 0; c8 < 8; ++c8) {
      int k = 256 + sec * 64 + c8 * 8;
      bs8 hv = *(const bs8*)(zs + zbyte(row, k));
#pragma unroll
      for (int e = 0; e < 8; ++e) {
        float hf = bf2f((unsigned short)hv[e]);
        int u = sec * 64 + c8 * 8 + e;
        s0 += hf * wdl[u][0];
        s1 += hf * wdl[u][1];
      }
    }
    ypart[row][0][sec] = s0;
    ypart[row][1][sec] = s1;
  }
  __syncthreads();
  if (tid < 32) {
    int b = tid >> 1, oc = tid & 1;
    float s = bd[oc0 + oc];
#pragma unroll
    for (int q = 0; q < 8; ++q) s += ypart[b][oc][q];
    out[((size_t)(b_base + b) * Tt + (Tt - 1)) * Oo + oc0 + oc] = s;
  }
}

extern "C" void kernel_launch(void* const* d_in, const int* in_sizes, int n_in,
                              void* d_out, int out_size, void* d_ws, size_t ws_size,
                              hipStream_t stream) {
  const float* x  = (const float*)d_in[0];
  const float* Wx = (const float*)d_in[1];
  const float* Wh = (const float*)d_in[2];
  const float* bs = (const float*)d_in[3];
  const float* Wd = (const float*)d_in[4];
  const float* bd = (const float*)d_in[5];
  float* out = (float*)d_out;

  unsigned short* hbuf = (unsigned short*)d_ws;                       // 2*256*512 bf16 = 512 KiB
  unsigned* bar = (unsigned*)((char*)d_ws + (size_t)2 * Bb * Uu * 2); // 16 groups * 32 flags

  rnn_init_bar<<<1, 512, 0, stream>>>(bar);
  rnn_lstm_kernel<<<dim3(512), dim3(256), 0, stream>>>(x, Wx, Wh, bs, Wd, bd, out, hbuf, bar);
}

// Round 11
// 2735.372 us; speedup vs baseline: 1.1109x; 1.0419x over previous
//
#include <hip/hip_runtime.h>

// LSTM surrogate: B=256, T=512, D=256, U=512, O=64.
// R11 = R8 (proven 2580us structure: flag published IMMEDIATELY after pointwise
// drain; window work after) + two overlap-only additions:
//  (1) x-part MFMA for t+1 precomputed in the consume window (post-load path
//      drops 24->16 MFMAs),
//  (2) per-wave 8-producer consume: poll own 8 flags (one 32B request, no
//      dependent loop), issue all 8x8B loads in flight, overlap with x-MFMA/
//      y-reduce, ds_write last. 4 barriers/step (was 5).
// Swap-at-L3 coherence protocol (R8) unchanged; 8B h-swaps (4B doubled WRITE).
// 16 batch-groups x 16 rows, 32 unit-groups -> grid 512, 2 blocks/CU.

#define Bb 256
#define Tt 512
#define Dd 256
#define Uu 512
#define Oo 64

typedef short bs8 __attribute__((ext_vector_type(8)));      // 8 bf16 (bits)
typedef float f32x4 __attribute__((ext_vector_type(4)));

__device__ __forceinline__ unsigned short f2bf(float f) {
  unsigned u = __float_as_uint(f);
  u += 0x7fffu + ((u >> 16) & 1u);                          // RNE
  return (unsigned short)(u >> 16);
}
__device__ __forceinline__ float bf2f(unsigned short s) {
  return __uint_as_float(((unsigned)s) << 16);
}
__device__ __forceinline__ float sigm(float v) { return 1.0f / (1.0f + __expf(-v)); }
__device__ __forceinline__ float tanhfast(float v) { return 2.0f / (1.0f + __expf(-2.0f * v)) - 1.0f; }

// z LDS: [16 rows][768 k] bf16, row stride 1536 B. XOR swizzle on 16B granules.
__device__ __forceinline__ int zbyte(int row, int k) {
  return (row * 1536 + k * 2) ^ ((row & 7) << 4);
}

__global__ void rnn_init_bar(unsigned* bar) {
  __hip_atomic_store(&bar[threadIdx.x], 0u, __ATOMIC_RELAXED, __HIP_MEMORY_SCOPE_AGENT);
}

__launch_bounds__(256, 2)
__global__ void rnn_lstm_kernel(const float* __restrict__ x, const float* __restrict__ Wx,
                                const float* __restrict__ Wh, const float* __restrict__ bias,
                                const float* __restrict__ Wd, const float* __restrict__ bd,
                                float* __restrict__ out, unsigned short* hbuf, unsigned* bar) {
  __shared__ __align__(16) char zs[16 * 768 * 2];   // 24576 B
  __shared__ float gates[4][16][17];                // [gate][row][unit], pad
  __shared__ float wdl[512][2];                     // Wd slice for this block's 2 out cols
  __shared__ float ypart[16][2][16];                // [row][oc][sec]

  const int tid = threadIdx.x;
  const int lane = tid & 63;
  const int wid = tid >> 6;                         // wave 0..3 == gate id
  const int bid = blockIdx.x;
  const int bg = (bid & 7) | ((bid >> 8) << 3);     // 0..15 (XCD-affine heuristic)
  const int ug = (bid >> 3) & 31;                   // 0..31
  const int b_base = bg * 16;
  const int u_base = ug * 16;
  const int oc0 = ug * 2;

  unsigned* fl = bar + bg * 32;  // 32 per-block flags, one 128B line per group

  // ---- weight slice as B-fragments: wave w = gate w; col=lane&15, k=(lane>>4)*8+e ----
  bs8 breg[24];
  {
    const int gc = wid * 512 + u_base + (lane & 15);
    const int kfr = (lane >> 4) * 8;
#pragma unroll
    for (int ks = 0; ks < 24; ++ks) {
      bs8 bb;
#pragma unroll
      for (int e = 0; e < 8; ++e) {
        int kg = ks * 32 + kfr + e;
        float w = (kg < 256) ? Wx[(size_t)kg * 2048 + gc]
                             : Wh[(size_t)(kg - 256) * 2048 + gc];
        bb[e] = (short)f2bf(w);
      }
      breg[ks] = bb;
    }
  }

  // pointwise (tid<64): prow=tid&15, us4=tid>>4 (0..3), units us4*4+{0..3}, 8B swap
  const int prow = tid & 15;
  const int usec = tid >> 4;                        // 0..15 (y-decode sections)
  const int us4 = usec & 3;
  float bi[4], bff[4], bgg[4], boo[4];
  if (tid < 64) {
#pragma unroll
    for (int j = 0; j < 4; ++j) {
      int ugl = u_base + us4 * 4 + j;
      bi[j]  = bias[0 * 512 + ugl];
      bff[j] = bias[1 * 512 + ugl];
      bgg[j] = bias[2 * 512 + ugl];
      boo[j] = bias[3 * 512 + ugl];
    }
  }
  float cst[4] = {0.f, 0.f, 0.f, 0.f};

  // ---- prologue: Wd->LDS, stage x_0, zero h-region ----
#pragma unroll
  for (int i = 0; i < 4; ++i) {
    int c = tid + i * 256;
    int u = c >> 1, oc = c & 1;
    wdl[u][oc] = Wd[(size_t)u * Oo + oc0 + oc];
  }
  {
    int row = tid >> 4;
    int d0 = (tid & 15) * 16;
    const float* xp = x + ((size_t)(b_base + row) * Tt + 0) * Dd + d0;
    float4 v0 = *(const float4*)xp;
    float4 v1 = *(const float4*)(xp + 4);
    float4 v2 = *(const float4*)(xp + 8);
    float4 v3 = *(const float4*)(xp + 12);
    bs8 p0, p1;
    p0[0] = (short)f2bf(v0.x); p0[1] = (short)f2bf(v0.y);
    p0[2] = (short)f2bf(v0.z); p0[3] = (short)f2bf(v0.w);
    p0[4] = (short)f2bf(v1.x); p0[5] = (short)f2bf(v1.y);
    p0[6] = (short)f2bf(v1.z); p0[7] = (short)f2bf(v1.w);
    p1[0] = (short)f2bf(v2.x); p1[1] = (short)f2bf(v2.y);
    p1[2] = (short)f2bf(v2.z); p1[3] = (short)f2bf(v2.w);
    p1[4] = (short)f2bf(v3.x); p1[5] = (short)f2bf(v3.y);
    p1[6] = (short)f2bf(v3.z); p1[7] = (short)f2bf(v3.w);
    *(bs8*)(zs + zbyte(row, d0)) = p0;
    *(bs8*)(zs + zbyte(row, d0 + 8)) = p1;
  }
#pragma unroll
  for (int i = 0; i < 4; ++i) {
    int c = tid + i * 256;
    int row = c >> 6;
    int u0 = (c & 63) * 8;
    bs8 zz = {0, 0, 0, 0, 0, 0, 0, 0};
    *(bs8*)(zs + zbyte(row, 256 + u0)) = zz;
  }
  __syncthreads();

  const int arow = lane & 15;
  const int akf = (lane >> 4) * 8;
  // x-part MFMA for t=0 (K=0..255)
  f32x4 accx0 = {0, 0, 0, 0}, accx1 = {0, 0, 0, 0};
#pragma unroll
  for (int ks = 0; ks < 8; ks += 2) {
    bs8 av0 = *(const bs8*)(zs + zbyte(arow, ks * 32 + akf));
    bs8 av1 = *(const bs8*)(zs + zbyte(arow, (ks + 1) * 32 + akf));
    accx0 = __builtin_amdgcn_mfma_f32_16x16x32_bf16(av0, breg[ks], accx0, 0, 0, 0);
    accx1 = __builtin_amdgcn_mfma_f32_16x16x32_bf16(av1, breg[ks + 1], accx1, 0, 0, 0);
  }

  // per-wave consume geometry: wave wid owns producers wid*8..wid*8+7
  const int cp = wid * 8 + (lane >> 3);             // this lane's producer
  const int ca = lane & 7;                          // sub-lane 0..7 -> rows 2a,2a+1

  for (int t = 0; t < Tt; ++t) {
    // ---- h-part MFMA (K=256..767), seeded with precomputed x-part ----
    f32x4 acc0 = accx0, acc1 = accx1;
#pragma unroll
    for (int ks = 8; ks < 24; ks += 2) {
      bs8 av0 = *(const bs8*)(zs + zbyte(arow, ks * 32 + akf));
      bs8 av1 = *(const bs8*)(zs + zbyte(arow, (ks + 1) * 32 + akf));
      acc0 = __builtin_amdgcn_mfma_f32_16x16x32_bf16(av0, breg[ks], acc0, 0, 0, 0);
      acc1 = __builtin_amdgcn_mfma_f32_16x16x32_bf16(av1, breg[ks + 1], acc1, 0, 0, 0);
    }
    acc0 += acc1;
    // C/D (HW-verified): col = lane&15, row = (lane>>4)*4 + reg
    {
      const int u16 = lane & 15;
      const int rb = (lane >> 4) * 4;
#pragma unroll
      for (int j = 0; j < 4; ++j) gates[wid][rb + j][u16] = acc0[j];
    }
    __syncthreads();                                        // s1

    // ---- pointwise (tid<64): 4 units, one 8B swap (executes at L3) ----
    if (tid < 64) {
      unsigned long long hpack = 0ull;
#pragma unroll
      for (int j = 0; j < 4; ++j) {
        int u = us4 * 4 + j;
        float gi = gates[0][prow][u] + bi[j];
        float gf = gates[1][prow][u] + bff[j];
        float gg = gates[2][prow][u] + bgg[j];
        float go = gates[3][prow][u] + boo[j];
        float iv = sigm(gi), fv = sigm(gf), gv = tanhfast(gg), ov = sigm(go);
        float cn = fv * cst[j] + iv * gv;
        cst[j] = cn;
        float hv = ov * tanhfast(cn);
        hpack |= ((unsigned long long)f2bf(hv)) << (16 * j);
      }
      unsigned long long* hp =
          (unsigned long long*)(hbuf + (size_t)(t & 1) * Bb * Uu +
                                (size_t)(b_base + prow) * Uu + u_base + us4 * 4);
      unsigned long long old = __hip_atomic_exchange(hp, hpack, __ATOMIC_RELAXED,
                                                     __HIP_MEMORY_SCOPE_AGENT);
      asm volatile("" :: "v"(old));   // keep the returning (executes-at-L3) form
    }
    __syncthreads();                                        // s2 (drains swaps at L3)
    if (tid == 0) {                   // flag IMMEDIATELY (others' polls wait on this)
      unsigned oldf = __hip_atomic_exchange(&fl[ug], (unsigned)(t + 1),
                                            __ATOMIC_RELAXED, __HIP_MEMORY_SCOPE_AGENT);
      asm volatile("" :: "v"(oldf));
    }

    // ---- window (after flag): x-stage x_{t+1} + y_{t-1} decode, all 256 ----
    if (t + 1 < Tt) {
      int row = tid >> 4;
      int d0 = (tid & 15) * 16;
      const float* xp = x + ((size_t)(b_base + row) * Tt + (t + 1)) * Dd + d0;
      float4 v0 = *(const float4*)xp;
      float4 v1 = *(const float4*)(xp + 4);
      float4 v2 = *(const float4*)(xp + 8);
      float4 v3 = *(const float4*)(xp + 12);
      bs8 p0, p1;
      p0[0] = (short)f2bf(v0.x); p0[1] = (short)f2bf(v0.y);
      p0[2] = (short)f2bf(v0.z); p0[3] = (short)f2bf(v0.w);
      p0[4] = (short)f2bf(v1.x); p0[5] = (short)f2bf(v1.y);
      p0[6] = (short)f2bf(v1.z); p0[7] = (short)f2bf(v1.w);
      p1[0] = (short)f2bf(v2.x); p1[1] = (short)f2bf(v2.y);
      p1[2] = (short)f2bf(v2.z); p1[3] = (short)f2bf(v2.w);
      p1[4] = (short)f2bf(v3.x); p1[5] = (short)f2bf(v3.y);
      p1[6] = (short)f2bf(v3.z); p1[7] = (short)f2bf(v3.w);
      *(bs8*)(zs + zbyte(row, d0)) = p0;
      *(bs8*)(zs + zbyte(row, d0 + 8)) = p1;
    }
    if (t > 0) {                      // y_{t-1} decode from zs.h (= h_{t-1})
      float s0 = 0.f, s1 = 0.f;
#pragma unroll
      for (int c8 = 0; c8 < 4; ++c8) {
        int k = 256 + usec * 32 + c8 * 8;
        bs8 hv = *(const bs8*)(zs + zbyte(prow, k));
#pragma unroll
        for (int e = 0; e < 8; ++e) {
          float hf = bf2f((unsigned short)hv[e]);
          int u = usec * 32 + c8 * 8 + e;
          s0 += hf * wdl[u][0];
          s1 += hf * wdl[u][1];
        }
      }
      ypart[prow][0][usec] = s0;
      ypart[prow][1][usec] = s1;
    }
    __syncthreads();                                        // s3

    // ---- per-wave consume: poll own 8 producers, issue 8x8B loads in flight ----
    const unsigned short* hsrc = hbuf + (size_t)(t & 1) * Bb * Uu;
    {
      unsigned v;
      do {
        v = __hip_atomic_load(&fl[wid * 8 + (lane & 7)], __ATOMIC_RELAXED,
                              __HIP_MEMORY_SCOPE_AGENT);
      } while (__any((int)(v < (unsigned)(t + 1))));
    }
    __builtin_amdgcn_sched_barrier(0);
    unsigned long long cd0, cd1, cd2, cd3, cd4, cd5, cd6, cd7;
    {
      const unsigned long long* p0 = (const unsigned long long*)
          (hsrc + (size_t)(b_base + ca * 2) * Uu + cp * 16);
      const unsigned long long* p1 = (const unsigned long long*)
          (hsrc + (size_t)(b_base + ca * 2 + 1) * Uu + cp * 16);
      cd0 = __hip_atomic_load(p0 + 0, __ATOMIC_RELAXED, __HIP_MEMORY_SCOPE_AGENT);
      cd1 = __hip_atomic_load(p0 + 1, __ATOMIC_RELAXED, __HIP_MEMORY_SCOPE_AGENT);
      cd2 = __hip_atomic_load(p0 + 2, __ATOMIC_RELAXED, __HIP_MEMORY_SCOPE_AGENT);
      cd3 = __hip_atomic_load(p0 + 3, __ATOMIC_RELAXED, __HIP_MEMORY_SCOPE_AGENT);
      cd4 = __hip_atomic_load(p1 + 0, __ATOMIC_RELAXED, __HIP_MEMORY_SCOPE_AGENT);
      cd5 = __hip_atomic_load(p1 + 1, __ATOMIC_RELAXED, __HIP_MEMORY_SCOPE_AGENT);
      cd6 = __hip_atomic_load(p1 + 2, __ATOMIC_RELAXED, __HIP_MEMORY_SCOPE_AGENT);
      cd7 = __hip_atomic_load(p1 + 3, __ATOMIC_RELAXED, __HIP_MEMORY_SCOPE_AGENT);
    }
    // overlap while loads return: x-part MFMA for t+1 (zs.x staged pre-s3)
    if (t + 1 < Tt) {
      f32x4 ax0 = {0, 0, 0, 0}, ax1 = {0, 0, 0, 0};
#pragma unroll
      for (int ks = 0; ks < 8; ks += 2) {
        bs8 av0 = *(const bs8*)(zs + zbyte(arow, ks * 32 + akf));
        bs8 av1 = *(const bs8*)(zs + zbyte(arow, (ks + 1) * 32 + akf));
        ax0 = __builtin_amdgcn_mfma_f32_16x16x32_bf16(av0, breg[ks], ax0, 0, 0, 0);
        ax1 = __builtin_amdgcn_mfma_f32_16x16x32_bf16(av1, breg[ks + 1], ax1, 0, 0, 0);
      }
      accx0 = ax0; accx1 = ax1;
    }
    if (t > 0 && tid < 32) {          // y-reduce (half of wave0)
      int b = tid >> 1, oc = tid & 1;
      float s = bd[oc0 + oc];
#pragma unroll
      for (int q = 0; q < 16; ++q) s += ypart[b][oc][q];
      out[((size_t)(b_base + b) * Tt + (t - 1)) * Oo + oc0 + oc] = s;
    }
    // land consume data in zs.h
    {
      int r0 = ca * 2, r1 = ca * 2 + 1;
      *(unsigned long long*)(zs + zbyte(r0, 256 + cp * 16 + 0))  = cd0;
      *(unsigned long long*)(zs + zbyte(r0, 256 + cp * 16 + 4))  = cd1;
      *(unsigned long long*)(zs + zbyte(r0, 256 + cp * 16 + 8))  = cd2;
      *(unsigned long long*)(zs + zbyte(r0, 256 + cp * 16 + 12)) = cd3;
      *(unsigned long long*)(zs + zbyte(r1, 256 + cp * 16 + 0))  = cd4;
      *(unsigned long long*)(zs + zbyte(r1, 256 + cp * 16 + 4))  = cd5;
      *(unsigned long long*)(zs + zbyte(r1, 256 + cp * 16 + 8))  = cd6;
      *(unsigned long long*)(zs + zbyte(r1, 256 + cp * 16 + 12)) = cd7;
    }
    __syncthreads();                                        // s4
  }

  // ---- epilogue: y_{T-1} from zs.h (= h_{T-1} after final consume) ----
  {
    float s0 = 0.f, s1 = 0.f;
#pragma unroll
    for (int c8 = 0; c8 < 4; ++c8) {
      int k = 256 + usec * 32 + c8 * 8;
      bs8 hv = *(const bs8*)(zs + zbyte(prow, k));
#pragma unroll
      for (int e = 0; e < 8; ++e) {
        float hf = bf2f((unsigned short)hv[e]);
        int u = usec * 32 + c8 * 8 + e;
        s0 += hf * wdl[u][0];
        s1 += hf * wdl[u][1];
      }
    }
    ypart[prow][0][usec] = s0;
    ypart[prow][1][usec] = s1;
  }
  __syncthreads();
  if (tid < 32) {
    int b = tid >> 1, oc = tid & 1;
    float s = bd[oc0 + oc];
#pragma unroll
    for (int q = 0; q < 16; ++q) s += ypart[b][oc][q];
    out[((size_t)(b_base + b) * Tt + (Tt - 1)) * Oo + oc0 + oc] = s;
  }
}

extern "C" void kernel_launch(void* const* d_in, const int* in_sizes, int n_in,
                              void* d_out, int out_size, void* d_ws, size_t ws_size,
                              hipStream_t stream) {
  const float* x  = (const float*)d_in[0];
  const float* Wx = (const float*)d_in[1];
  const float* Wh = (const float*)d_in[2];
  const float* bs = (const float*)d_in[3];
  const float* Wd = (const float*)d_in[4];
  const float* bd = (const float*)d_in[5];
  float* out = (float*)d_out;

  unsigned short* hbuf = (unsigned short*)d_ws;                       // 2*256*512 bf16 = 512 KiB
  unsigned* bar = (unsigned*)((char*)d_ws + (size_t)2 * Bb * Uu * 2); // 16 groups * 32 flags

  rnn_init_bar<<<1, 512, 0, stream>>>(bar);
  rnn_lstm_kernel<<<dim3(512), dim3(256), 0, stream>>>(x, Wx, Wh, bs, Wd, bd, out, hbuf, bar);
}

// Round 12
// 2423.759 us; speedup vs baseline: 1.2537x; 1.1286x over previous
//
#include <hip/hip_runtime.h>

// LSTM surrogate: B=256, T=512, D=256, U=512, O=64.
// R12 = R8 verbatim (proven 2580us; R9/R10/R11 restructures all regressed)
// + ONE protocol change: de-hotspot the barrier flags.
//   (a) flags spread one-per-128B-line (was: 32 flags in ONE line absorbing
//       32 spinning pollers + 32 swaps -> L3 slice queueing = latency+variance)
//   (b) s_sleep(2) backoff in the poll loop (cuts re-issue pressure ~10x).
// Swap-at-L3 coherence protocol unchanged.
// 16 batch-groups x 16 rows, 32 unit-groups -> grid 512, 2 blocks/CU.

#define Bb 256
#define Tt 512
#define Dd 256
#define Uu 512
#define Oo 64

typedef short bs8 __attribute__((ext_vector_type(8)));      // 8 bf16 (bits)
typedef float f32x4 __attribute__((ext_vector_type(4)));

__device__ __forceinline__ unsigned short f2bf(float f) {
  unsigned u = __float_as_uint(f);
  u += 0x7fffu + ((u >> 16) & 1u);                          // RNE
  return (unsigned short)(u >> 16);
}
__device__ __forceinline__ float bf2f(unsigned short s) {
  return __uint_as_float(((unsigned)s) << 16);
}
__device__ __forceinline__ float sigm(float v) { return 1.0f / (1.0f + __expf(-v)); }
__device__ __forceinline__ float tanhfast(float v) { return 2.0f / (1.0f + __expf(-2.0f * v)) - 1.0f; }

// z LDS: [16 rows][768 k] bf16, row stride 1536 B. XOR swizzle on 16B granules.
__device__ __forceinline__ int zbyte(int row, int k) {
  return (row * 1536 + k * 2) ^ ((row & 7) << 4);
}

// flags: group g, block i -> bar[(g*32 + i)*32]  (one 128B line per flag)
__global__ void rnn_init_bar(unsigned* bar) {
  for (int i = threadIdx.x; i < 16 * 32 * 32; i += 256)
    __hip_atomic_store(&bar[i], 0u, __ATOMIC_RELAXED, __HIP_MEMORY_SCOPE_AGENT);
}

__launch_bounds__(256, 2)
__global__ void rnn_lstm_kernel(const float* __restrict__ x, const float* __restrict__ Wx,
                                const float* __restrict__ Wh, const float* __restrict__ bias,
                                const float* __restrict__ Wd, const float* __restrict__ bd,
                                float* __restrict__ out, unsigned short* hbuf, unsigned* bar) {
  __shared__ __align__(16) char zs[16 * 768 * 2];   // 24576 B
  __shared__ float gates[4][16][17];                // [gate][row][unit], pad
  __shared__ float wdl[512][2];                     // Wd slice for this block's 2 out cols
  __shared__ float ypart[16][2][16];                // [row][oc][usec]

  const int tid = threadIdx.x;
  const int lane = tid & 63;
  const int wid = tid >> 6;                         // wave 0..3 == gate id
  const int bid = blockIdx.x;
  const int bg = (bid & 7) | ((bid >> 8) << 3);     // 0..15 (XCD-affine heuristic)
  const int ug = (bid >> 3) & 31;                   // 0..31
  const int b_base = bg * 16;
  const int u_base = ug * 16;
  const int oc0 = ug * 2;

  unsigned* fl = bar + bg * 32 * 32;  // 32 flags, each on its OWN 128B line

  // ---- weight slice as B-fragments: wave w = gate w; col=lane&15, k=(lane>>4)*8+e ----
  bs8 breg[24];
  {
    const int gc = wid * 512 + u_base + (lane & 15);
    const int kfr = (lane >> 4) * 8;
#pragma unroll
    for (int ks = 0; ks < 24; ++ks) {
      bs8 bb;
#pragma unroll
      for (int e = 0; e < 8; ++e) {
        int kg = ks * 32 + kfr + e;
        float w = (kg < 256) ? Wx[(size_t)kg * 2048 + gc]
                             : Wh[(size_t)(kg - 256) * 2048 + gc];
        bb[e] = (short)f2bf(w);
      }
      breg[ks] = bb;
    }
  }

  // pointwise ownership (tid<64): row = tid&15, us4 = tid>>4 (0..3), units us4*4+{0..3}
  const int prow = tid & 15;
  const int usec = tid >> 4;                        // 0..15 (y-decode sections of 32 units)
  const int us4 = usec & 3;
  float bi[4], bff[4], bgg[4], boo[4];
  if (tid < 64) {
#pragma unroll
    for (int j = 0; j < 4; ++j) {
      int ugl = u_base + us4 * 4 + j;
      bi[j]  = bias[0 * 512 + ugl];
      bff[j] = bias[1 * 512 + ugl];
      bgg[j] = bias[2 * 512 + ugl];
      boo[j] = bias[3 * 512 + ugl];
    }
  }
  float cst[4] = {0.f, 0.f, 0.f, 0.f};

  union U16 { unsigned long long q[2]; bs8 v; };

  // ---- prologue: Wd slice to LDS, stage x_0, zero h-region ----
#pragma unroll
  for (int i = 0; i < 4; ++i) {
    int c = tid + i * 256;
    int u = c >> 1, oc = c & 1;
    wdl[u][oc] = Wd[(size_t)u * Oo + oc0 + oc];
  }
  {
    int row = tid >> 4;
    int d0 = (tid & 15) * 16;
    const float* xp = x + ((size_t)(b_base + row) * Tt + 0) * Dd + d0;
    float4 v0 = *(const float4*)xp;
    float4 v1 = *(const float4*)(xp + 4);
    float4 v2 = *(const float4*)(xp + 8);
    float4 v3 = *(const float4*)(xp + 12);
    bs8 p0, p1;
    p0[0] = (short)f2bf(v0.x); p0[1] = (short)f2bf(v0.y);
    p0[2] = (short)f2bf(v0.z); p0[3] = (short)f2bf(v0.w);
    p0[4] = (short)f2bf(v1.x); p0[5] = (short)f2bf(v1.y);
    p0[6] = (short)f2bf(v1.z); p0[7] = (short)f2bf(v1.w);
    p1[0] = (short)f2bf(v2.x); p1[1] = (short)f2bf(v2.y);
    p1[2] = (short)f2bf(v2.z); p1[3] = (short)f2bf(v2.w);
    p1[4] = (short)f2bf(v3.x); p1[5] = (short)f2bf(v3.y);
    p1[6] = (short)f2bf(v3.z); p1[7] = (short)f2bf(v3.w);
    *(bs8*)(zs + zbyte(row, d0)) = p0;
    *(bs8*)(zs + zbyte(row, d0 + 8)) = p1;
  }
#pragma unroll
  for (int i = 0; i < 4; ++i) {
    int c = tid + i * 256;
    int row = c >> 6;
    int u0 = (c & 63) * 8;
    bs8 zz = {0, 0, 0, 0, 0, 0, 0, 0};
    *(bs8*)(zs + zbyte(row, 256 + u0)) = zz;
  }
  __syncthreads();

  for (int t = 0; t < Tt; ++t) {
    // ---- gates MFMA: each wave computes its gate's [16 rows x 16 units], K=768 ----
    f32x4 acc0 = {0, 0, 0, 0}, acc1 = {0, 0, 0, 0};
    {
      const int arow = lane & 15;
      const int akf = (lane >> 4) * 8;
#pragma unroll
      for (int ks = 0; ks < 24; ks += 2) {
        bs8 av0 = *(const bs8*)(zs + zbyte(arow, ks * 32 + akf));
        bs8 av1 = *(const bs8*)(zs + zbyte(arow, (ks + 1) * 32 + akf));
        acc0 = __builtin_amdgcn_mfma_f32_16x16x32_bf16(av0, breg[ks], acc0, 0, 0, 0);
        acc1 = __builtin_amdgcn_mfma_f32_16x16x32_bf16(av1, breg[ks + 1], acc1, 0, 0, 0);
      }
      acc0 += acc1;
    }
    // C/D (HW-verified): col = lane&15, row = (lane>>4)*4 + reg
    {
      const int u16 = lane & 15;
      const int rb = (lane >> 4) * 4;
#pragma unroll
      for (int j = 0; j < 4; ++j) gates[wid][rb + j][u16] = acc0[j];
    }
    __syncthreads();

    // ---- pointwise LSTM cell (tid<64); h published via atomic swap_x2 ----
    // swap executes at L3 (returns old, sc0): its vmcnt-ack == L3 visibility.
    if (tid < 64) {
      unsigned long long hpack = 0ull;
#pragma unroll
      for (int j = 0; j < 4; ++j) {
        int u = us4 * 4 + j;
        float gi = gates[0][prow][u] + bi[j];
        float gf = gates[1][prow][u] + bff[j];
        float gg = gates[2][prow][u] + bgg[j];
        float go = gates[3][prow][u] + boo[j];
        float iv = sigm(gi), fv = sigm(gf), gv = tanhfast(gg), ov = sigm(go);
        float cn = fv * cst[j] + iv * gv;
        cst[j] = cn;
        float hv = ov * tanhfast(cn);
        hpack |= ((unsigned long long)f2bf(hv)) << (16 * j);
      }
      unsigned long long* hp =
          (unsigned long long*)(hbuf + (size_t)(t & 1) * Bb * Uu +
                                (size_t)(b_base + prow) * Uu + u_base + us4 * 4);
      unsigned long long old = __hip_atomic_exchange(hp, hpack, __ATOMIC_RELAXED,
                                                     __HIP_MEMORY_SCOPE_AGENT);
      asm volatile("" :: "v"(old));   // keep the returning (executes-at-L3) form
    }
    // barrier drains each wave's vmcnt: all h-swaps have EXECUTED AT L3 here.
    __syncthreads();
    if (tid == 0) {
      unsigned oldf = __hip_atomic_exchange(&fl[ug * 32], (unsigned)(t + 1),
                                            __ATOMIC_RELAXED, __HIP_MEMORY_SCOPE_AGENT);
      asm volatile("" :: "v"(oldf));
    }

    // ---- barrier window: stage x_{t+1} (x-region of zs is dead) ----
    if (t + 1 < Tt) {
      int row = tid >> 4;
      int d0 = (tid & 15) * 16;
      const float* xp = x + ((size_t)(b_base + row) * Tt + (t + 1)) * Dd + d0;
      float4 v0 = *(const float4*)xp;
      float4 v1 = *(const float4*)(xp + 4);
      float4 v2 = *(const float4*)(xp + 8);
      float4 v3 = *(const float4*)(xp + 12);
      bs8 p0, p1;
      p0[0] = (short)f2bf(v0.x); p0[1] = (short)f2bf(v0.y);
      p0[2] = (short)f2bf(v0.z); p0[3] = (short)f2bf(v0.w);
      p0[4] = (short)f2bf(v1.x); p0[5] = (short)f2bf(v1.y);
      p0[6] = (short)f2bf(v1.z); p0[7] = (short)f2bf(v1.w);
      p1[0] = (short)f2bf(v2.x); p1[1] = (short)f2bf(v2.y);
      p1[2] = (short)f2bf(v2.z); p1[3] = (short)f2bf(v2.w);
      p1[4] = (short)f2bf(v3.x); p1[5] = (short)f2bf(v3.y);
      p1[6] = (short)f2bf(v3.z); p1[7] = (short)f2bf(v3.w);
      *(bs8*)(zs + zbyte(row, d0)) = p0;
      *(bs8*)(zs + zbyte(row, d0 + 8)) = p1;
    }

    // ---- barrier window: y_{t-1} partials from LDS h copy ----
    if (t > 0) {
      float s0 = 0.f, s1 = 0.f;
#pragma unroll
      for (int c8 = 0; c8 < 4; ++c8) {
        int k = 256 + usec * 32 + c8 * 8;
        bs8 hv = *(const bs8*)(zs + zbyte(prow, k));
#pragma unroll
        for (int e = 0; e < 8; ++e) {
          float hf = bf2f((unsigned short)hv[e]);
          int u = usec * 32 + c8 * 8 + e;
          s0 += hf * wdl[u][0];
          s1 += hf * wdl[u][1];
        }
      }
      ypart[prow][0][usec] = s0;
      ypart[prow][1][usec] = s1;
    }
    __syncthreads();
    // y reduce on wave0, poll on wave1 (parallel), s_sleep backoff
    if (t > 0 && tid < 32) {
      int b = tid >> 1, oc = tid & 1;
      float s = bd[oc0 + oc];
#pragma unroll
      for (int q = 0; q < 16; ++q) s += ypart[b][oc][q];
      out[((size_t)(b_base + b) * Tt + (t - 1)) * Oo + oc0 + oc] = s;
    }
    if (wid == 1) {
      for (;;) {
        unsigned v = __hip_atomic_load(&fl[(lane & 31) * 32], __ATOMIC_RELAXED,
                                       __HIP_MEMORY_SCOPE_AGENT);
        if (!__any((int)(v < (unsigned)(t + 1)))) break;
        __builtin_amdgcn_s_sleep(2);
      }
    }
    __builtin_amdgcn_sched_barrier(0);
    __syncthreads();

    // ---- stage h_t from hbuf[t&1] (bulk, coalesced, all loads in flight) ----
    {
      const unsigned short* hsrc = hbuf + (size_t)(t & 1) * Bb * Uu;
#pragma unroll
      for (int i = 0; i < 4; ++i) {
        int c = tid + i * 256;
        int row = c >> 6;
        int u0 = (c & 63) * 8;
        const unsigned long long* p =
            (const unsigned long long*)(hsrc + (size_t)(b_base + row) * Uu + u0);
        U16 uu;
        uu.q[0] = __hip_atomic_load(p, __ATOMIC_RELAXED, __HIP_MEMORY_SCOPE_AGENT);
        uu.q[1] = __hip_atomic_load(p + 1, __ATOMIC_RELAXED, __HIP_MEMORY_SCOPE_AGENT);
        *(bs8*)(zs + zbyte(row, 256 + u0)) = uu.v;
      }
    }
    __syncthreads();
  }

  // ---- epilogue: y_{T-1} (h_{T-1} staged by final iteration) ----
  {
    float s0 = 0.f, s1 = 0.f;
#pragma unroll
    for (int c8 = 0; c8 < 4; ++c8) {
      int k = 256 + usec * 32 + c8 * 8;
      bs8 hv = *(const bs8*)(zs + zbyte(prow, k));
#pragma unroll
      for (int e = 0; e < 8; ++e) {
        float hf = bf2f((unsigned short)hv[e]);
        int u = usec * 32 + c8 * 8 + e;
        s0 += hf * wdl[u][0];
        s1 += hf * wdl[u][1];
      }
    }
    ypart[prow][0][usec] = s0;
    ypart[prow][1][usec] = s1;
    __syncthreads();
    if (tid < 32) {
      int b = tid >> 1, oc = tid & 1;
      float s = bd[oc0 + oc];
#pragma unroll
      for (int q = 0; q < 16; ++q) s += ypart[b][oc][q];
      out[((size_t)(b_base + b) * Tt + (Tt - 1)) * Oo + oc0 + oc] = s;
    }
  }
}

extern "C" void kernel_launch(void* const* d_in, const int* in_sizes, int n_in,
                              void* d_out, int out_size, void* d_ws, size_t ws_size,
                              hipStream_t stream) {
  const float* x  = (const float*)d_in[0];
  const float* Wx = (const float*)d_in[1];
  const float* Wh = (const float*)d_in[2];
  const float* bs = (const float*)d_in[3];
  const float* Wd = (const float*)d_in[4];
  const float* bd = (const float*)d_in[5];
  float* out = (float*)d_out;

  unsigned short* hbuf = (unsigned short*)d_ws;                       // 2*256*512 bf16 = 512 KiB
  unsigned* bar = (unsigned*)((char*)d_ws + (size_t)2 * Bb * Uu * 2); // 16g * 32 flags * 128B

  rnn_init_bar<<<1, 256, 0, stream>>>(bar);
  rnn_lstm_kernel<<<dim3(512), dim3(256), 0, stream>>>(x, Wx, Wh, bs, Wd, bd, out, hbuf, bar);
}